// Round 3
// baseline (153.912 us; speedup 1.0000x reference)
//
#include <hip/hip_runtime.h>
#include <math.h>

// Problem constants (match reference)
constexpr int B_ = 32;
constexpr int C_ = 32;
constexpr int RES_ = 16;
constexpr int G_ = RES_ * RES_ * RES_;   // 4096
constexpr int N_ = 16384;
constexpr int H_ = 64;
// sqrt(3)/RES
__device__ constexpr float REG_THR = 0.10825317547305483f;

// ---------------------------------------------------------------------------
// Kernel 1: per-batch inclusive scan of counts (4096 cells) -> cum[b][G].
// ---------------------------------------------------------------------------
__global__ __launch_bounds__(256) void scan_kernel(const int* __restrict__ counts,
                                                   int* __restrict__ cum) {
    const int b = blockIdx.x;
    const int* cb = counts + b * G_;
    int* ob = cum + b * G_;

    __shared__ int partials[256];
    const int t = threadIdx.x;
    const int base = t * 16;

    int local[16];
    int s = 0;
#pragma unroll
    for (int i = 0; i < 16; ++i) {
        s += cb[base + i];
        local[i] = s;
    }
    partials[t] = s;
    __syncthreads();

    for (int off = 1; off < 256; off <<= 1) {
        int v = (t >= off) ? partials[t - off] : 0;
        __syncthreads();
        partials[t] += v;
        __syncthreads();
    }
    const int prev = (t > 0) ? partials[t - 1] : 0;

#pragma unroll
    for (int i = 0; i < 16; ++i) ob[base + i] = prev + local[i];
}

// ---------------------------------------------------------------------------
// Kernel 2 (Stage A): hx[b, cell, h] = b1[h] + sum_c W1[h,c] * x[b,c,cell]
// One thread per (b, cell); x loads fully coalesced (consecutive cells per
// lane); weights wave-uniform -> SGPR operands. 268M FMA total.
// ---------------------------------------------------------------------------
__global__ __launch_bounds__(256) void hx_kernel(const float* __restrict__ x,
                                                 const float* __restrict__ W1,
                                                 const float* __restrict__ b1,
                                                 float* __restrict__ hx) {
    const int b = blockIdx.y;
    const int cell = blockIdx.x * 256 + threadIdx.x;

    const float* xb = x + ((size_t)b * C_) * G_ + cell;
    float xv[C_];
#pragma unroll
    for (int c = 0; c < C_; ++c) xv[c] = xb[(size_t)c * G_];

    float* ob = hx + ((size_t)b * G_ + cell) * H_;
#pragma unroll 2
    for (int hc = 0; hc < H_ / 4; ++hc) {
        float a[4];
#pragma unroll
        for (int j = 0; j < 4; ++j) {
            const int h = hc * 4 + j;
            float acc = b1[h];
            const float* w = W1 + h * 34;
#pragma unroll
            for (int c = 0; c < C_; ++c) acc = fmaf(w[c], xv[c], acc);
            a[j] = acc;
        }
        *(float4*)(ob + hc * 4) = make_float4(a[0], a[1], a[2], a[3]);
    }
}

// ---------------------------------------------------------------------------
// Kernel 3 (Stage B): one thread per (b, n) point.
//   idx = searchsorted(cum[b], n, 'right')  (binary search, LDS copy)
//   h   = relu(hx[b, idx, :] + W1[:,32]*r0 + W1[:,33]*r1)   (128 FMA)
//   out = W2 @ h + b2                                        (192 FMA)
//   out += grid_o[:, idx];  reg = max(||out|| - sqrt(3)/RES, 0)
// hx row is 256 B contiguous; adjacent points share cells -> L1/L2 hits.
// ---------------------------------------------------------------------------
__global__ __launch_bounds__(256) void point_kernel(
    const float* __restrict__ hx, const float* __restrict__ b_rnd,
    const float* __restrict__ grid_o, const float* __restrict__ W1,
    const float* __restrict__ W2, const float* __restrict__ b2,
    const int* __restrict__ cum, float* __restrict__ out0,
    float* __restrict__ reg_out) {
    const int b = blockIdx.y;
    const int n = blockIdx.x * 256 + threadIdx.x;
    const int t = threadIdx.x;

    __shared__ int s_cum[G_];
    const int* cb = cum + b * G_;
#pragma unroll
    for (int i = 0; i < G_ / 256; ++i) s_cum[t + i * 256] = cb[t + i * 256];
    __syncthreads();

    int lo = 0, hi = G_ - 1;
#pragma unroll
    for (int it = 0; it < 12; ++it) {
        const int mid = (lo + hi) >> 1;
        if (s_cum[mid] > n) hi = mid; else lo = mid + 1;
        if (lo >= hi) hi = lo;
    }
    const int idx = lo;

    const float r0 = b_rnd[((size_t)b * 2 + 0) * N_ + n];
    const float r1 = b_rnd[((size_t)b * 2 + 1) * N_ + n];
    const float* hp = hx + ((size_t)b * G_ + idx) * H_;

    float o0 = b2[0], o1 = b2[1], o2 = b2[2];
#pragma unroll 4
    for (int hc = 0; hc < H_ / 4; ++hc) {
        const float4 v = *(const float4*)(hp + hc * 4);
        const float vv[4] = {v.x, v.y, v.z, v.w};
#pragma unroll
        for (int j = 0; j < 4; ++j) {
            const int h = hc * 4 + j;
            float hv = vv[j];
            hv = fmaf(W1[h * 34 + 32], r0, hv);
            hv = fmaf(W1[h * 34 + 33], r1, hv);
            hv = fmaxf(hv, 0.0f);
            o0 = fmaf(W2[0 * H_ + h], hv, o0);
            o1 = fmaf(W2[1 * H_ + h], hv, o1);
            o2 = fmaf(W2[2 * H_ + h], hv, o2);
        }
    }

    const float nrm = sqrtf(o0 * o0 + o1 * o1 + o2 * o2);
    const float reg = fmaxf(nrm - REG_THR, 0.0f);

    o0 += grid_o[0 * G_ + idx];
    o1 += grid_o[1 * G_ + idx];
    o2 += grid_o[2 * G_ + idx];

    float* p = out0 + ((size_t)b * 3) * N_ + n;
    p[0]              = o0;
    p[N_]             = o1;
    p[2 * (size_t)N_] = o2;
    reg_out[(size_t)b * N_ + n] = reg;
}

// ---------------------------------------------------------------------------
extern "C" void kernel_launch(void* const* d_in, const int* in_sizes, int n_in,
                              void* d_out, int out_size, void* d_ws, size_t ws_size,
                              hipStream_t stream) {
    const float* x      = (const float*)d_in[0];  // (B, C, RES, RES, RES)
    const int*   counts = (const int*)  d_in[1];  // (B, G)
    const float* b_rnd  = (const float*)d_in[2];  // (B, 2, N)
    const float* grid_o = (const float*)d_in[3];  // (3, G)
    const float* W1     = (const float*)d_in[4];  // (H, C+2)
    const float* b1     = (const float*)d_in[5];  // (H,)
    const float* W2     = (const float*)d_in[6];  // (3, H)
    const float* b2     = (const float*)d_in[7];  // (3,)

    float* out  = (float*)d_out;                      // (B, 3, N) then (B, N)
    float* rout = out + (size_t)B_ * 3 * N_;

    int*   cum = (int*)d_ws;                          // B*G ints   = 512 KB
    float* hx  = (float*)((char*)d_ws + (size_t)B_ * G_ * sizeof(int));
                                                      // B*G*H fp32 = 33.5 MB

    scan_kernel<<<B_, 256, 0, stream>>>(counts, cum);

    dim3 gridA(G_ / 256, B_);
    hx_kernel<<<gridA, 256, 0, stream>>>(x, W1, b1, hx);

    dim3 gridB(N_ / 256, B_);
    point_kernel<<<gridB, 256, 0, stream>>>(hx, b_rnd, grid_o, W1, W2, b2,
                                            cum, out, rout);
}

// Round 4
// 130.993 us; speedup vs baseline: 1.1750x; 1.1750x over previous
//
#include <hip/hip_runtime.h>
#include <math.h>

// Problem constants (match reference)
constexpr int B_ = 32;
constexpr int C_ = 32;
constexpr int RES_ = 16;
constexpr int G_ = RES_ * RES_ * RES_;   // 4096
constexpr int N_ = 16384;
constexpr int H_ = 64;
// sqrt(3)/RES
__device__ constexpr float REG_THR = 0.10825317547305483f;

// ---------------------------------------------------------------------------
// Kernel 1: per-batch inclusive scan of counts (4096 cells) -> cum[b][G].
// ---------------------------------------------------------------------------
__global__ __launch_bounds__(256) void scan_kernel(const int* __restrict__ counts,
                                                   int* __restrict__ cum) {
    const int b = blockIdx.x;
    const int* cb = counts + b * G_;
    int* ob = cum + b * G_;

    __shared__ int partials[256];
    const int t = threadIdx.x;
    const int base = t * 16;

    int local[16];
    int s = 0;
#pragma unroll
    for (int i = 0; i < 16; ++i) {
        s += cb[base + i];
        local[i] = s;
    }
    partials[t] = s;
    __syncthreads();

    for (int off = 1; off < 256; off <<= 1) {
        int v = (t >= off) ? partials[t - off] : 0;
        __syncthreads();
        partials[t] += v;
        __syncthreads();
    }
    const int prev = (t > 0) ? partials[t - 1] : 0;

#pragma unroll
    for (int i = 0; i < 16; ++i) ob[base + i] = prev + local[i];
}

// ---------------------------------------------------------------------------
// Kernel 2 (Stage A): hx[b, cell, h] = b1[h] + sum_c W1[h,c] * x[b,c,cell]
//
// Round-3 version scattered 16 B per lane into 64 distinct cache lines per
// store instr (lane stride 256 B) -> 5.8x HBM write amplification
// (WRITE_SIZE 193 MB for a 33.5 MB buffer). Fix: compute the tile into LDS
// (padded, conflict-free), then copy out LINEARLY so consecutive lanes write
// consecutive addresses -> full 64B/128B lines per wave store.
//
// Tile: 128 cells per block, 256 threads = 2 threads/cell (h 0..31 | 32..63).
// LDS: 128 x 65 floats (pad +1) = 33.3 KB -> 4 blocks/CU.
// ---------------------------------------------------------------------------
constexpr int TILE_CELLS = 128;
constexpr int PAD = H_ + 1;   // 65: +1 pad => LDS b32 ops conflict-free

__global__ __launch_bounds__(256) void hx_kernel(const float* __restrict__ x,
                                                 const float* __restrict__ W1,
                                                 const float* __restrict__ b1,
                                                 float* __restrict__ hx) {
    const int b = blockIdx.y;
    const int tile = blockIdx.x * TILE_CELLS;
    const int t = threadIdx.x;
    const int cell_l = t & (TILE_CELLS - 1);   // t % 128
    const int hh = (t >> 7) * 32;              // 0 or 32

    __shared__ float s_hx[TILE_CELLS * PAD];

    // Coalesced x loads: lanes 0..63 -> 64 consecutive cells.
    const float* xb = x + ((size_t)b * C_) * G_ + tile + cell_l;
    float xv[C_];
#pragma unroll
    for (int c = 0; c < C_; ++c) xv[c] = xb[(size_t)c * G_];

    // Compute this thread's 32 h-values; scalar LDS writes (bank-free: pad).
    float* row = s_hx + cell_l * PAD + hh;
#pragma unroll 8
    for (int j = 0; j < 32; ++j) {
        const int h = hh + j;
        float acc = b1[h];
        const float* w = W1 + h * 34;
#pragma unroll
        for (int c = 0; c < C_; ++c) acc = fmaf(w[c], xv[c], acc);
        row[j] = acc;
    }
    __syncthreads();

    // Linear coalesced copy-out: 128*64 = 8192 floats = 2048 float4.
    float* ob = hx + ((size_t)b * G_ + tile) * H_;
#pragma unroll
    for (int k = 0; k < 8; ++k) {
        const int L = (t + k * 256) * 4;       // linear float index
        const int cell = L >> 6;               // L / 64
        const int h = L & 63;
        const float* s = s_hx + cell * PAD + h;
        *(float4*)(ob + L) = make_float4(s[0], s[1], s[2], s[3]);
    }
}

// ---------------------------------------------------------------------------
// Kernel 3 (Stage B): one thread per (b, n) point.
//   idx = searchsorted(cum[b], n, 'right')  (binary search, LDS copy)
//   h   = relu(hx[b, idx, :] + W1[:,32]*r0 + W1[:,33]*r1)
//   out = W2 @ h + b2;  out += grid_o[:, idx];  reg = clip(||out|| - thr, 0)
// ---------------------------------------------------------------------------
__global__ __launch_bounds__(256) void point_kernel(
    const float* __restrict__ hx, const float* __restrict__ b_rnd,
    const float* __restrict__ grid_o, const float* __restrict__ W1,
    const float* __restrict__ W2, const float* __restrict__ b2,
    const int* __restrict__ cum, float* __restrict__ out0,
    float* __restrict__ reg_out) {
    const int b = blockIdx.y;
    const int n = blockIdx.x * 256 + threadIdx.x;
    const int t = threadIdx.x;

    __shared__ int s_cum[G_];
    const int* cb = cum + b * G_;
#pragma unroll
    for (int i = 0; i < G_ / 256; ++i) s_cum[t + i * 256] = cb[t + i * 256];
    __syncthreads();

    int lo = 0, hi = G_ - 1;
#pragma unroll
    for (int it = 0; it < 12; ++it) {
        const int mid = (lo + hi) >> 1;
        if (s_cum[mid] > n) hi = mid; else lo = mid + 1;
        if (lo >= hi) hi = lo;
    }
    const int idx = lo;

    const float r0 = b_rnd[((size_t)b * 2 + 0) * N_ + n];
    const float r1 = b_rnd[((size_t)b * 2 + 1) * N_ + n];
    const float* hp = hx + ((size_t)b * G_ + idx) * H_;

    float o0 = b2[0], o1 = b2[1], o2 = b2[2];
#pragma unroll 4
    for (int hc = 0; hc < H_ / 4; ++hc) {
        const float4 v = *(const float4*)(hp + hc * 4);
        const float vv[4] = {v.x, v.y, v.z, v.w};
#pragma unroll
        for (int j = 0; j < 4; ++j) {
            const int h = hc * 4 + j;
            float hv = vv[j];
            hv = fmaf(W1[h * 34 + 32], r0, hv);
            hv = fmaf(W1[h * 34 + 33], r1, hv);
            hv = fmaxf(hv, 0.0f);
            o0 = fmaf(W2[0 * H_ + h], hv, o0);
            o1 = fmaf(W2[1 * H_ + h], hv, o1);
            o2 = fmaf(W2[2 * H_ + h], hv, o2);
        }
    }

    const float nrm = sqrtf(o0 * o0 + o1 * o1 + o2 * o2);
    const float reg = fmaxf(nrm - REG_THR, 0.0f);

    o0 += grid_o[0 * G_ + idx];
    o1 += grid_o[1 * G_ + idx];
    o2 += grid_o[2 * G_ + idx];

    float* p = out0 + ((size_t)b * 3) * N_ + n;
    p[0]              = o0;
    p[N_]             = o1;
    p[2 * (size_t)N_] = o2;
    reg_out[(size_t)b * N_ + n] = reg;
}

// ---------------------------------------------------------------------------
extern "C" void kernel_launch(void* const* d_in, const int* in_sizes, int n_in,
                              void* d_out, int out_size, void* d_ws, size_t ws_size,
                              hipStream_t stream) {
    const float* x      = (const float*)d_in[0];  // (B, C, RES, RES, RES)
    const int*   counts = (const int*)  d_in[1];  // (B, G)
    const float* b_rnd  = (const float*)d_in[2];  // (B, 2, N)
    const float* grid_o = (const float*)d_in[3];  // (3, G)
    const float* W1     = (const float*)d_in[4];  // (H, C+2)
    const float* b1     = (const float*)d_in[5];  // (H,)
    const float* W2     = (const float*)d_in[6];  // (3, H)
    const float* b2     = (const float*)d_in[7];  // (3,)

    float* out  = (float*)d_out;                      // (B, 3, N) then (B, N)
    float* rout = out + (size_t)B_ * 3 * N_;

    int*   cum = (int*)d_ws;                          // B*G ints   = 512 KB
    float* hx  = (float*)((char*)d_ws + (size_t)B_ * G_ * sizeof(int));
                                                      // B*G*H fp32 = 33.5 MB

    scan_kernel<<<B_, 256, 0, stream>>>(counts, cum);

    dim3 gridA(G_ / TILE_CELLS, B_);
    hx_kernel<<<gridA, 256, 0, stream>>>(x, W1, b1, hx);

    dim3 gridB(N_ / 256, B_);
    point_kernel<<<gridB, 256, 0, stream>>>(hx, b_rnd, grid_o, W1, W2, b2,
                                            cum, out, rout);
}

// Round 5
// 117.451 us; speedup vs baseline: 1.3104x; 1.1153x over previous
//
#include <hip/hip_runtime.h>
#include <math.h>

// Problem constants (match reference)
constexpr int B_ = 32;
constexpr int C_ = 32;
constexpr int RES_ = 16;
constexpr int G_ = RES_ * RES_ * RES_;   // 4096
constexpr int N_ = 16384;
constexpr int H_ = 64;
// sqrt(3)/RES
__device__ constexpr float REG_THR = 0.10825317547305483f;

// ---------------------------------------------------------------------------
// Kernel 1: per-batch inclusive scan of counts (4096 cells) -> cum[b][G].
// ---------------------------------------------------------------------------
__global__ __launch_bounds__(256) void scan_kernel(const int* __restrict__ counts,
                                                   int* __restrict__ cum) {
    const int b = blockIdx.x;
    const int* cb = counts + b * G_;
    int* ob = cum + b * G_;

    __shared__ int partials[256];
    const int t = threadIdx.x;
    const int base = t * 16;

    int local[16];
    int s = 0;
#pragma unroll
    for (int i = 0; i < 16; ++i) {
        s += cb[base + i];
        local[i] = s;
    }
    partials[t] = s;
    __syncthreads();

    for (int off = 1; off < 256; off <<= 1) {
        int v = (t >= off) ? partials[t - off] : 0;
        __syncthreads();
        partials[t] += v;
        __syncthreads();
    }
    const int prev = (t > 0) ? partials[t - 1] : 0;

#pragma unroll
    for (int i = 0; i < 16; ++i) ob[base + i] = prev + local[i];
}

// ---------------------------------------------------------------------------
// Kernel 2 (Stage A): hx[b, cell, h] = b1[h] + sum_c W1[h,c] * x[b,c,cell]
//
// Round-4 bottleneck: hh = (t>>7)*32 is divergent to the compiler, so every
// W1 read was a per-lane global_load_dword (1024/thread, L1-hit but
// issue/latency bound -> 43 us @ VALUBusy 21%). hh IS per-wave uniform
// (waves 0-1: 0, waves 2-3: 32); readfirstlane makes that provable ->
// weights become s_load_dwordx* with SGPR operands in v_fma_f32.
//
// Tile: 128 cells/block, 256 threads = 2 threads/cell (h 0..31 | 32..63).
// LDS: 128 x 65 floats (pad +1 -> compute-writes conflict-free), then
// linear coalesced copy-out (fixes the 5.8x write amplification of round 3).
// ---------------------------------------------------------------------------
constexpr int TILE_CELLS = 128;
constexpr int PAD = H_ + 1;   // 65

__global__ __launch_bounds__(256) void hx_kernel(const float* __restrict__ x,
                                                 const float* __restrict__ W1,
                                                 const float* __restrict__ b1,
                                                 float* __restrict__ hx) {
    const int b = blockIdx.y;
    const int tile = blockIdx.x * TILE_CELLS;
    const int t = threadIdx.x;
    const int cell_l = t & (TILE_CELLS - 1);   // t % 128
    // Per-wave uniform h-offset, made provably uniform -> scalar weight loads.
    const int hh = __builtin_amdgcn_readfirstlane((t >> 7) * 32);

    __shared__ float s_hx[TILE_CELLS * PAD];

    // Coalesced x loads: lanes -> consecutive cells.
    const float* xb = x + ((size_t)b * C_) * G_ + tile + cell_l;
    float xv[C_];
#pragma unroll
    for (int c = 0; c < C_; ++c) xv[c] = xb[(size_t)c * G_];

    // 32 h-values per thread; weights at wave-uniform addresses (s_load).
    float* row = s_hx + cell_l * PAD + hh;
#pragma unroll 8
    for (int j = 0; j < 32; ++j) {
        const int h = hh + j;
        float acc = b1[h];
        const float* w = W1 + h * 34;
#pragma unroll
        for (int c = 0; c < C_; ++c) acc = fmaf(w[c], xv[c], acc);
        row[j] = acc;
    }
    __syncthreads();

    // Linear coalesced copy-out: 128*64 = 8192 floats = 2048 float4.
    float* ob = hx + ((size_t)b * G_ + tile) * H_;
#pragma unroll
    for (int k = 0; k < 8; ++k) {
        const int L = (t + k * 256) * 4;       // linear float index
        const int cell = L >> 6;               // L / 64
        const int h = L & 63;
        const float* s = s_hx + cell * PAD + h;
        *(float4*)(ob + L) = make_float4(s[0], s[1], s[2], s[3]);
    }
}

// ---------------------------------------------------------------------------
// Kernel 3 (Stage B): one thread per (b, n) point.
//   idx = searchsorted(cum[b], n, 'right')  (binary search, LDS copy)
//   h   = relu(hx[b, idx, :] + W1[:,32]*r0 + W1[:,33]*r1)
//   out = W2 @ h + b2;  out += grid_o[:, idx];  reg = clip(||out|| - thr, 0)
// Weight addresses here are loop-uniform (h is a loop index) -> s_load.
// ---------------------------------------------------------------------------
__global__ __launch_bounds__(256) void point_kernel(
    const float* __restrict__ hx, const float* __restrict__ b_rnd,
    const float* __restrict__ grid_o, const float* __restrict__ W1,
    const float* __restrict__ W2, const float* __restrict__ b2,
    const int* __restrict__ cum, float* __restrict__ out0,
    float* __restrict__ reg_out) {
    const int b = blockIdx.y;
    const int n = blockIdx.x * 256 + threadIdx.x;
    const int t = threadIdx.x;

    __shared__ int s_cum[G_];
    const int* cb = cum + b * G_;
#pragma unroll
    for (int i = 0; i < G_ / 256; ++i) s_cum[t + i * 256] = cb[t + i * 256];
    __syncthreads();

    int lo = 0, hi = G_ - 1;
#pragma unroll
    for (int it = 0; it < 12; ++it) {
        const int mid = (lo + hi) >> 1;
        if (s_cum[mid] > n) hi = mid; else lo = mid + 1;
        if (lo >= hi) hi = lo;
    }
    const int idx = lo;

    const float r0 = b_rnd[((size_t)b * 2 + 0) * N_ + n];
    const float r1 = b_rnd[((size_t)b * 2 + 1) * N_ + n];
    const float* hp = hx + ((size_t)b * G_ + idx) * H_;

    float o0 = b2[0], o1 = b2[1], o2 = b2[2];
#pragma unroll 4
    for (int hc = 0; hc < H_ / 4; ++hc) {
        const float4 v = *(const float4*)(hp + hc * 4);
        const float vv[4] = {v.x, v.y, v.z, v.w};
#pragma unroll
        for (int j = 0; j < 4; ++j) {
            const int h = hc * 4 + j;
            float hv = vv[j];
            hv = fmaf(W1[h * 34 + 32], r0, hv);
            hv = fmaf(W1[h * 34 + 33], r1, hv);
            hv = fmaxf(hv, 0.0f);
            o0 = fmaf(W2[0 * H_ + h], hv, o0);
            o1 = fmaf(W2[1 * H_ + h], hv, o1);
            o2 = fmaf(W2[2 * H_ + h], hv, o2);
        }
    }

    const float nrm = sqrtf(o0 * o0 + o1 * o1 + o2 * o2);
    const float reg = fmaxf(nrm - REG_THR, 0.0f);

    o0 += grid_o[0 * G_ + idx];
    o1 += grid_o[1 * G_ + idx];
    o2 += grid_o[2 * G_ + idx];

    float* p = out0 + ((size_t)b * 3) * N_ + n;
    p[0]              = o0;
    p[N_]             = o1;
    p[2 * (size_t)N_] = o2;
    reg_out[(size_t)b * N_ + n] = reg;
}

// ---------------------------------------------------------------------------
extern "C" void kernel_launch(void* const* d_in, const int* in_sizes, int n_in,
                              void* d_out, int out_size, void* d_ws, size_t ws_size,
                              hipStream_t stream) {
    const float* x      = (const float*)d_in[0];  // (B, C, RES, RES, RES)
    const int*   counts = (const int*)  d_in[1];  // (B, G)
    const float* b_rnd  = (const float*)d_in[2];  // (B, 2, N)
    const float* grid_o = (const float*)d_in[3];  // (3, G)
    const float* W1     = (const float*)d_in[4];  // (H, C+2)
    const float* b1     = (const float*)d_in[5];  // (H,)
    const float* W2     = (const float*)d_in[6];  // (3, H)
    const float* b2     = (const float*)d_in[7];  // (3,)

    float* out  = (float*)d_out;                      // (B, 3, N) then (B, N)
    float* rout = out + (size_t)B_ * 3 * N_;

    int*   cum = (int*)d_ws;                          // B*G ints   = 512 KB
    float* hx  = (float*)((char*)d_ws + (size_t)B_ * G_ * sizeof(int));
                                                      // B*G*H fp32 = 33.5 MB

    scan_kernel<<<B_, 256, 0, stream>>>(counts, cum);

    dim3 gridA(G_ / TILE_CELLS, B_);
    hx_kernel<<<gridA, 256, 0, stream>>>(x, W1, b1, hx);

    dim3 gridB(N_ / 256, B_);
    point_kernel<<<gridB, 256, 0, stream>>>(hx, b_rnd, grid_o, W1, W2, b2,
                                            cum, out, rout);
}